// Round 3
// baseline (115.166 us; speedup 1.0000x reference)
//
#include <hip/hip_runtime.h>
#include <math.h>

// B=2, L=512, C=768, C/3=256, pairDim=128
// mo/mt stored in ws as [B,32,L,64] _Float16 (4 MB each)

typedef __attribute__((ext_vector_type(8))) _Float16 half8;
typedef __attribute__((ext_vector_type(4))) _Float16 half4;
typedef __attribute__((ext_vector_type(4))) float f32x4;

#define MFMA_F16(a,b,c) __builtin_amdgcn_mfma_f32_16x16x32_f16((a),(b),(c),0,0,0)

static __device__ inline unsigned pack2f16(float a, float b) {
    _Float16 ha = (_Float16)a, hb = (_Float16)b;
    unsigned short ua = __builtin_bit_cast(unsigned short, ha);
    unsigned short ub = __builtin_bit_cast(unsigned short, hb);
    return (unsigned)ua | ((unsigned)ub << 16);
}

static __device__ inline half8 cvt8(float4 u, float4 v) {
    half8 h;
    h[0] = (_Float16)u.x; h[1] = (_Float16)u.y; h[2] = (_Float16)u.z; h[3] = (_Float16)u.w;
    h[4] = (_Float16)v.x; h[5] = (_Float16)v.y; h[6] = (_Float16)v.z; h[7] = (_Float16)v.w;
    return h;
}

__global__ __launch_bounds__(256) void k1_rowstage(
    const float* __restrict__ x, const float* __restrict__ ln_w, const float* __restrict__ ln_b,
    const float* __restrict__ W1, const float* __restrict__ b1,
    const float* __restrict__ Wa, const float* __restrict__ ba,
    _Float16* __restrict__ mo_g, _Float16* __restrict__ mt_g)
{
    const int bl  = blockIdx.x;          // b*512 + l
    const int tid = threadIdx.x;
    const int b   = bl >> 9;
    const int l   = bl & 511;
    const int w   = tid >> 6;
    const int lane = tid & 63;
    const int lr  = lane & 15;
    const int lk  = lane >> 4;

    __shared__ float hs[768];
    __shared__ float ts[768];
    __shared__ float mos[32 * 68];       // padded stride 68 (2-way max on b128 frag reads)
    __shared__ float ws1[4], ws2[4];

    const float* xrow = x + (size_t)bl * 768;
    float v0 = xrow[tid], v1 = xrow[tid + 256], v2 = xrow[tid + 512];

    // Wa fragments for GEMM2 (A-operand: row d = w*16+lr, k-slice e = ks*32+lk*8)
    half8 waf[2];
    #pragma unroll
    for (int ks = 0; ks < 2; ++ks) {
        const float* wp = Wa + (size_t)(w * 16 + lr) * 64 + ks * 32 + lk * 8;
        waf[ks] = cvt8(*(const float4*)wp, *(const float4*)(wp + 4));
    }
    const float4 baq = *(const float4*)(ba + w * 16 + lk * 4);

    // LayerNorm stats
    float s1 = v0 + v1 + v2;
    float s2 = v0 * v0 + v1 * v1 + v2 * v2;
    #pragma unroll
    for (int off = 32; off > 0; off >>= 1) {
        s1 += __shfl_down(s1, off);
        s2 += __shfl_down(s2, off);
    }
    if ((tid & 63) == 0) { ws1[tid >> 6] = s1; ws2[tid >> 6] = s2; }
    __syncthreads();
    float tot1 = ws1[0] + ws1[1] + ws1[2] + ws1[3];
    float tot2 = ws2[0] + ws2[1] + ws2[2] + ws2[3];
    float mu   = tot1 * (1.0f / 768.0f);
    float var  = tot2 * (1.0f / 768.0f) - mu * mu;
    float rstd = rsqrtf(var + 1e-6f);

    hs[tid]       = (v0 - mu) * rstd * ln_w[tid]       + ln_b[tid];
    hs[tid + 256] = (v1 - mu) * rstd * ln_w[tid + 256] + ln_b[tid + 256];
    hs[tid + 512] = (v2 - mu) * rstd * ln_w[tid + 512] + ln_b[tid + 512];
    __syncthreads();

    // GEMM1 (f32 VALU): t[k][j] = h[k] . W1[j,:] + b1[j]
    {
        float a0 = 0.f, a1 = 0.f, a2 = 0.f;
        const float4* wrow = (const float4*)(W1 + (size_t)tid * 256);
        const float4* h0 = (const float4*)(hs);
        const float4* h1 = (const float4*)(hs + 256);
        const float4* h2 = (const float4*)(hs + 512);
        #pragma unroll 8
        for (int i4 = 0; i4 < 64; i4++) {
            float4 wv = wrow[i4];
            float4 x0 = h0[i4], x1 = h1[i4], x2 = h2[i4];
            a0 += x0.x * wv.x + x0.y * wv.y + x0.z * wv.z + x0.w * wv.w;
            a1 += x1.x * wv.x + x1.y * wv.y + x1.z * wv.z + x1.w * wv.w;
            a2 += x2.x * wv.x + x2.y * wv.y + x2.z * wv.z + x2.w * wv.w;
        }
        float bb = b1[tid];
        ts[tid]       = a0 + bb;
        ts[tid + 256] = a1 + bb;
        ts[tid + 512] = a2 + bb;
    }
    __syncthreads();

    // outer product -> mos (LDS, padded) + mo_g (f16)
    {
        const int c = tid >> 3, i = tid & 7;
        float ti0 = ts[c * 8 + i], ti1 = ts[256 + c * 8 + i], ti2 = ts[512 + c * 8 + i];
        half8 h8;
        #pragma unroll
        for (int j = 0; j < 8; j++) {
            float m = (ti0 * ts[c * 8 + j] + ti1 * ts[256 + c * 8 + j] + ti2 * ts[512 + c * 8 + j]) * (1.0f / 3.0f);
            mos[c * 68 + i * 8 + j] = m;
            h8[j] = (_Float16)m;
        }
        size_t mobase = ((size_t)(b * 32 + c) * 512 + l) * 64 + i * 8;
        *(half8*)(mo_g + mobase) = h8;
    }
    __syncthreads();

    // GEMM2 (MFMA): mt[d][c] = gelu( sum_e Wa[d][e]*mo[c][e] + ba[d] )
    // wave w owns d-tile [w*16, w*16+16); N = 32 c (2 tiles); K = 64 (2 steps)
    #pragma unroll
    for (int nt = 0; nt < 2; ++nt) {
        f32x4 acc = { baq.x, baq.y, baq.z, baq.w };
        #pragma unroll
        for (int ks = 0; ks < 2; ++ks) {
            const float* mp = &mos[(nt * 16 + lr) * 68 + ks * 32 + lk * 8];
            half8 mof = cvt8(*(const float4*)mp, *(const float4*)(mp + 4));
            acc = MFMA_F16(waf[ks], mof, acc);
        }
        half4 o;
        #pragma unroll
        for (int j = 0; j < 4; ++j) {
            float g = 0.5f * acc[j] * (1.0f + erff(acc[j] * 0.70710678118654752f));
            o[j] = (_Float16)g;
        }
        // c = nt*16+lr (D col), d = w*16+lk*4+j (D row) -> 4 consecutive d, 8B store
        *(half4*)(mt_g + ((size_t)(b * 32 + nt * 16 + lr) * 512 + l) * 64 + w * 16 + lk * 4) = o;
    }
}

// k2: per (32 l x 16 m) tile:
//   phase A (MFMA): raw[pair][c] = MO[c,l,:].MT[c,m,:]  -> f16 in LDS (pad 40, XOR-swizzled)
//   phase B (MFMA, swapped): D[p][pair] = W2 . raw  -> float4 coalesced stores
__global__ __launch_bounds__(256, 4) void k2_mfma(
    const _Float16* __restrict__ mo, const _Float16* __restrict__ mt,
    const float* __restrict__ W2, const float* __restrict__ b2,
    float* __restrict__ out)
{
    __shared__ _Float16 raw16[512 * 40];   // [pair][c], 80B rows, 40 KB

    const int tid  = threadIdx.x;
    const int w    = tid >> 6;
    const int lane = tid & 63;
    const int lr   = lane & 15;
    const int lk   = lane >> 4;
    const int b    = blockIdx.z;
    const int m0   = blockIdx.x << 4;     // 32 m-tiles
    const int l0   = blockIdx.y << 5;     // 16 l-tiles

    // ---- phase A: wave w computes c in [8w, 8w+8), all 512 pairs ----
    #pragma unroll
    for (int cp = 0; cp < 4; ++cp) {
        const int c0 = w * 8 + cp * 2;
        f32x4 acc[2][2] = {};   // [ci][rh]
        #pragma unroll
        for (int ci = 0; ci < 2; ++ci) {
            const int c = c0 + ci;
            const _Float16* mo_c = mo + (((size_t)(b * 32 + c) * 512) + l0) * 64;
            const _Float16* mt_c = mt + (((size_t)(b * 32 + c) * 512) + m0) * 64;
            #pragma unroll
            for (int ks = 0; ks < 2; ++ks) {
                half8 bfrag = *(const half8*)(mt_c + (size_t)lr * 64 + ks * 32 + lk * 8);
                #pragma unroll
                for (int rh = 0; rh < 2; ++rh) {
                    half8 afrag = *(const half8*)(mo_c + (size_t)(rh * 16 + lr) * 64 + ks * 32 + lk * 8);
                    acc[ci][rh] = MFMA_F16(afrag, bfrag, acc[ci][rh]);
                }
            }
        }
        // park raw tile: pair = l_local*16 + m_local; D: row(l)=lk*4+j, col(m)=lr
        #pragma unroll
        for (int rh = 0; rh < 2; ++rh) {
            #pragma unroll
            for (int j = 0; j < 4; ++j) {
                int pair = (rh * 16 + lk * 4 + j) * 16 + lr;
                int sw   = (((pair >> 3) & 1) << 3) | (((pair >> 6) & 1) << 4);
                *(unsigned*)&raw16[pair * 40 + (c0 ^ sw)] = pack2f16(acc[0][rh][j], acc[1][rh][j]);
            }
        }
    }

    // W2 fragments (A-operand: row p = c8*16+lr, k-slice c = lk*8) + bias quads
    half8 wfrag[8]; float4 b2q[8];
    #pragma unroll
    for (int c8 = 0; c8 < 8; ++c8) {
        const float* wp = W2 + (size_t)(c8 * 16 + lr) * 32 + lk * 8;
        wfrag[c8] = cvt8(*(const float4*)wp, *(const float4*)(wp + 4));
        b2q[c8]   = *(const float4*)(b2 + c8 * 16 + lk * 4);
    }
    __syncthreads();

    // ---- phase B: wave w handles pair-row groups r in [8w, 8w+8) (r == l_local) ----
    #pragma unroll
    for (int i = 0; i < 8; ++i) {
        const int r  = w * 8 + i;
        const int pr = r * 16 + lr;
        const int swr = (((pr >> 3) & 1) << 3) | (((pr >> 6) & 1) << 4);
        half8 a = *(const half8*)&raw16[pr * 40 + ((lk * 8) ^ swr)];   // B-frag: col=pair, k=c
        float* ob = out + (((size_t)(b * 512 + l0 + r)) * 512 + m0 + lr) * 128;
        #pragma unroll
        for (int c8 = 0; c8 < 8; ++c8) {
            f32x4 d = { b2q[c8].x, b2q[c8].y, b2q[c8].z, b2q[c8].w };
            d = MFMA_F16(wfrag[c8], a, d);       // D[p][pair]
            *(f32x4*)(ob + c8 * 16 + lk * 4) = d; // 4 consecutive p -> float4
        }
    }
}

extern "C" void kernel_launch(void* const* d_in, const int* in_sizes, int n_in,
                              void* d_out, int out_size, void* d_ws, size_t ws_size,
                              hipStream_t stream) {
    const float* x    = (const float*)d_in[0];
    const float* ln_w = (const float*)d_in[1];
    const float* ln_b = (const float*)d_in[2];
    const float* W1   = (const float*)d_in[3];
    const float* b1   = (const float*)d_in[4];
    const float* Wa   = (const float*)d_in[5];
    const float* ba   = (const float*)d_in[6];
    const float* W2   = (const float*)d_in[7];
    const float* b2   = (const float*)d_in[8];
    float* out = (float*)d_out;

    _Float16* mo = (_Float16*)d_ws;                     // [2,32,512,64] f16 = 4 MB
    _Float16* mt = mo + (size_t)2 * 32 * 512 * 64;      // [2,32,512,64] f16 = 4 MB

    k1_rowstage<<<1024, 256, 0, stream>>>(x, ln_w, ln_b, W1, b1, Wa, ba, mo, mt);
    k2_mfma<<<dim3(32, 16, 2), 256, 0, stream>>>(mo, mt, W2, b2, out);
}

// Round 4
// 99.808 us; speedup vs baseline: 1.1539x; 1.1539x over previous
//
#include <hip/hip_runtime.h>
#include <math.h>

// B=2, L=512, C=768, C/3=256, pairDim=128
// mo/mt stored in ws as [B,32,L,64] _Float16 (4 MB each)

typedef __attribute__((ext_vector_type(8))) _Float16 half8;
typedef __attribute__((ext_vector_type(4))) _Float16 half4;
typedef __attribute__((ext_vector_type(4))) float f32x4;

#define MFMA_F16(a,b,c) __builtin_amdgcn_mfma_f32_16x16x32_f16((a),(b),(c),0,0,0)

static __device__ inline unsigned pack2f16(float a, float b) {
    _Float16 ha = (_Float16)a, hb = (_Float16)b;
    unsigned short ua = __builtin_bit_cast(unsigned short, ha);
    unsigned short ub = __builtin_bit_cast(unsigned short, hb);
    return (unsigned)ua | ((unsigned)ub << 16);
}

static __device__ inline half8 cvt8(float4 u, float4 v) {
    half8 h;
    h[0] = (_Float16)u.x; h[1] = (_Float16)u.y; h[2] = (_Float16)u.z; h[3] = (_Float16)u.w;
    h[4] = (_Float16)v.x; h[5] = (_Float16)v.y; h[6] = (_Float16)v.z; h[7] = (_Float16)v.w;
    return h;
}

__global__ __launch_bounds__(256) void k1_rowstage(
    const float* __restrict__ x, const float* __restrict__ ln_w, const float* __restrict__ ln_b,
    const float* __restrict__ W1, const float* __restrict__ b1,
    const float* __restrict__ Wa, const float* __restrict__ ba,
    _Float16* __restrict__ mo_g, _Float16* __restrict__ mt_g)
{
    const int bl  = blockIdx.x;          // b*512 + l
    const int tid = threadIdx.x;
    const int b   = bl >> 9;
    const int l   = bl & 511;
    const int w   = tid >> 6;
    const int lane = tid & 63;
    const int lr  = lane & 15;
    const int lk  = lane >> 4;

    __shared__ float hs[768];
    __shared__ float ts[768];
    __shared__ float mos[32 * 68];       // padded stride 68 (2-way max on b128 frag reads)
    __shared__ float ws1[4], ws2[4];

    const float* xrow = x + (size_t)bl * 768;
    float v0 = xrow[tid], v1 = xrow[tid + 256], v2 = xrow[tid + 512];

    // Wa fragments for GEMM2 (A-operand: row d = w*16+lr, k-slice e = ks*32+lk*8)
    half8 waf[2];
    #pragma unroll
    for (int ks = 0; ks < 2; ++ks) {
        const float* wp = Wa + (size_t)(w * 16 + lr) * 64 + ks * 32 + lk * 8;
        waf[ks] = cvt8(*(const float4*)wp, *(const float4*)(wp + 4));
    }
    const float4 baq = *(const float4*)(ba + w * 16 + lk * 4);

    // LayerNorm stats
    float s1 = v0 + v1 + v2;
    float s2 = v0 * v0 + v1 * v1 + v2 * v2;
    #pragma unroll
    for (int off = 32; off > 0; off >>= 1) {
        s1 += __shfl_down(s1, off);
        s2 += __shfl_down(s2, off);
    }
    if ((tid & 63) == 0) { ws1[tid >> 6] = s1; ws2[tid >> 6] = s2; }
    __syncthreads();
    float tot1 = ws1[0] + ws1[1] + ws1[2] + ws1[3];
    float tot2 = ws2[0] + ws2[1] + ws2[2] + ws2[3];
    float mu   = tot1 * (1.0f / 768.0f);
    float var  = tot2 * (1.0f / 768.0f) - mu * mu;
    float rstd = rsqrtf(var + 1e-6f);

    hs[tid]       = (v0 - mu) * rstd * ln_w[tid]       + ln_b[tid];
    hs[tid + 256] = (v1 - mu) * rstd * ln_w[tid + 256] + ln_b[tid + 256];
    hs[tid + 512] = (v2 - mu) * rstd * ln_w[tid + 512] + ln_b[tid + 512];
    __syncthreads();

    // GEMM1 (f32 VALU): t[k][j] = h[k] . W1[j,:] + b1[j]
    {
        float a0 = 0.f, a1 = 0.f, a2 = 0.f;
        const float4* wrow = (const float4*)(W1 + (size_t)tid * 256);
        const float4* h0 = (const float4*)(hs);
        const float4* h1 = (const float4*)(hs + 256);
        const float4* h2 = (const float4*)(hs + 512);
        #pragma unroll 8
        for (int i4 = 0; i4 < 64; i4++) {
            float4 wv = wrow[i4];
            float4 x0 = h0[i4], x1 = h1[i4], x2 = h2[i4];
            a0 += x0.x * wv.x + x0.y * wv.y + x0.z * wv.z + x0.w * wv.w;
            a1 += x1.x * wv.x + x1.y * wv.y + x1.z * wv.z + x1.w * wv.w;
            a2 += x2.x * wv.x + x2.y * wv.y + x2.z * wv.z + x2.w * wv.w;
        }
        float bb = b1[tid];
        ts[tid]       = a0 + bb;
        ts[tid + 256] = a1 + bb;
        ts[tid + 512] = a2 + bb;
    }
    __syncthreads();

    // outer product -> mos (LDS, padded) + mo_g (f16)
    {
        const int c = tid >> 3, i = tid & 7;
        float ti0 = ts[c * 8 + i], ti1 = ts[256 + c * 8 + i], ti2 = ts[512 + c * 8 + i];
        half8 h8;
        #pragma unroll
        for (int j = 0; j < 8; j++) {
            float m = (ti0 * ts[c * 8 + j] + ti1 * ts[256 + c * 8 + j] + ti2 * ts[512 + c * 8 + j]) * (1.0f / 3.0f);
            mos[c * 68 + i * 8 + j] = m;
            h8[j] = (_Float16)m;
        }
        size_t mobase = ((size_t)(b * 32 + c) * 512 + l) * 64 + i * 8;
        *(half8*)(mo_g + mobase) = h8;
    }
    __syncthreads();

    // GEMM2 (MFMA): mt[d][c] = gelu( sum_e Wa[d][e]*mo[c][e] + ba[d] )
    #pragma unroll
    for (int nt = 0; nt < 2; ++nt) {
        f32x4 acc = { baq.x, baq.y, baq.z, baq.w };
        #pragma unroll
        for (int ks = 0; ks < 2; ++ks) {
            const float* mp = &mos[(nt * 16 + lr) * 68 + ks * 32 + lk * 8];
            half8 mof = cvt8(*(const float4*)mp, *(const float4*)(mp + 4));
            acc = MFMA_F16(waf[ks], mof, acc);
        }
        half4 o;
        #pragma unroll
        for (int j = 0; j < 4; ++j) {
            float g = 0.5f * acc[j] * (1.0f + erff(acc[j] * 0.70710678118654752f));
            o[j] = (_Float16)g;
        }
        *(half4*)(mt_g + ((size_t)(b * 32 + nt * 16 + lr) * 512 + l) * 64 + w * 16 + lk * 4) = o;
    }
}

// k2: per (32 l x 16 m) tile:
//   phase A (MFMA): raw[pair][c] = MO[c,l,:].MT[c,m,:] -> f16 in LDS (pad 40, XOR-swizzled)
//   phase B (MFMA): D[p][pair] = W2 . raw, then per-wave LDS transpose ->
//                   8 x 1KB-contiguous nontemporal f32x4 stores per l-row
__global__ __launch_bounds__(256, 2) void k2_mfma(
    const _Float16* __restrict__ mo, const _Float16* __restrict__ mt,
    const float* __restrict__ W2, const float* __restrict__ b2,
    float* __restrict__ out)
{
    __shared__ _Float16 raw16[512 * 40];   // [pair][c], 80B rows, 40 KB
    __shared__ float sc[4][2048];          // per-wave 8KB transpose scratch, 32 KB

    const int tid  = threadIdx.x;
    const int w    = tid >> 6;
    const int lane = tid & 63;
    const int lr   = lane & 15;
    const int lk   = lane >> 4;

    // bijective XCD swizzle (nwg=1024, 1024%8==0): each XCD gets a contiguous chunk
    const int flat = blockIdx.x;
    const int nf   = (flat & 7) * 128 + (flat >> 3);
    const int m0   = (nf & 31) << 4;      // 32 m-tiles of 16
    const int l0   = ((nf >> 5) & 15) << 5; // 16 l-tiles of 32
    const int b    = nf >> 9;

    // ---- phase A: wave w computes c in [8w, 8w+8), all 512 pairs ----
    #pragma unroll
    for (int cp = 0; cp < 4; ++cp) {
        const int c0 = w * 8 + cp * 2;
        f32x4 acc[2][2] = {};   // [ci][rh]
        #pragma unroll
        for (int ci = 0; ci < 2; ++ci) {
            const int c = c0 + ci;
            const _Float16* mo_c = mo + (((size_t)(b * 32 + c) * 512) + l0) * 64;
            const _Float16* mt_c = mt + (((size_t)(b * 32 + c) * 512) + m0) * 64;
            #pragma unroll
            for (int ks = 0; ks < 2; ++ks) {
                half8 bfrag = *(const half8*)(mt_c + (size_t)lr * 64 + ks * 32 + lk * 8);
                #pragma unroll
                for (int rh = 0; rh < 2; ++rh) {
                    half8 afrag = *(const half8*)(mo_c + (size_t)(rh * 16 + lr) * 64 + ks * 32 + lk * 8);
                    acc[ci][rh] = MFMA_F16(afrag, bfrag, acc[ci][rh]);
                }
            }
        }
        // park raw tile: pair = l_local*16 + m_local; D: row(l)=lk*4+j, col(m)=lr
        #pragma unroll
        for (int rh = 0; rh < 2; ++rh) {
            #pragma unroll
            for (int j = 0; j < 4; ++j) {
                int pair = (rh * 16 + lk * 4 + j) * 16 + lr;
                int sw   = (((pair >> 3) & 1) << 3) | (((pair >> 6) & 1) << 4);
                *(unsigned*)&raw16[pair * 40 + (c0 ^ sw)] = pack2f16(acc[0][rh][j], acc[1][rh][j]);
            }
        }
    }

    // W2 fragments (A-operand: row p = c8*16+lr, k-slice c = lk*8) + bias quads
    half8 wfrag[8]; float4 b2q[8];
    #pragma unroll
    for (int c8 = 0; c8 < 8; ++c8) {
        const float* wp = W2 + (size_t)(c8 * 16 + lr) * 32 + lk * 8;
        wfrag[c8] = cvt8(*(const float4*)wp, *(const float4*)(wp + 4));
        b2q[c8]   = *(const float4*)(b2 + c8 * 16 + lk * 4);
    }
    __syncthreads();

    // ---- phase B: wave w handles l-rows r in [8w, 8w+8) ----
    for (int i = 0; i < 8; ++i) {
        const int r  = w * 8 + i;
        const int pr = r * 16 + lr;
        const int swr = (((pr >> 3) & 1) << 3) | (((pr >> 6) & 1) << 4);
        half8 a = *(const half8*)&raw16[pr * 40 + ((lk * 8) ^ swr)];   // B-frag: col=pair(m), k=c

        // compute D[p][m] for 16 m, 128 p; park in per-wave swizzled scratch
        #pragma unroll
        for (int c8 = 0; c8 < 8; ++c8) {
            f32x4 d = { b2q[c8].x, b2q[c8].y, b2q[c8].z, b2q[c8].w };
            d = MFMA_F16(wfrag[c8], a, d);
            // lane (lr,lk) holds p = c8*16+lk*4+j for m = lr
            int chunk = (c8 * 4 + lk) ^ lr;        // 16B-chunk swizzle by m-row
            *(f32x4*)&sc[w][lr * 128 + chunk * 4] = d;
        }
        // read back in store order: 8 x 1KB contiguous (full 8KB region for this l-row)
        float* ob = out + (((size_t)(b * 512 + l0 + r)) * 512 + m0) * 128;
        #pragma unroll
        for (int s = 0; s < 8; ++s) {
            int mm = s * 2 + (lane >> 5);
            int cp = (lane & 31) ^ mm;
            f32x4 v = *(const f32x4*)&sc[w][mm * 128 + cp * 4];
            __builtin_nontemporal_store(v, (f32x4*)(ob + s * 256 + lane * 4));
        }
    }
}

extern "C" void kernel_launch(void* const* d_in, const int* in_sizes, int n_in,
                              void* d_out, int out_size, void* d_ws, size_t ws_size,
                              hipStream_t stream) {
    const float* x    = (const float*)d_in[0];
    const float* ln_w = (const float*)d_in[1];
    const float* ln_b = (const float*)d_in[2];
    const float* W1   = (const float*)d_in[3];
    const float* b1   = (const float*)d_in[4];
    const float* Wa   = (const float*)d_in[5];
    const float* ba   = (const float*)d_in[6];
    const float* W2   = (const float*)d_in[7];
    const float* b2   = (const float*)d_in[8];
    float* out = (float*)d_out;

    _Float16* mo = (_Float16*)d_ws;                     // [2,32,512,64] f16 = 4 MB
    _Float16* mt = mo + (size_t)2 * 32 * 512 * 64;      // [2,32,512,64] f16 = 4 MB

    k1_rowstage<<<1024, 256, 0, stream>>>(x, ln_w, ln_b, W1, b1, Wa, ba, mo, mt);
    k2_mfma<<<1024, 256, 0, stream>>>(mo, mt, W2, b2, out);
}